// Round 10
// baseline (234.370 us; speedup 1.0000x reference)
//
#include <hip/hip_runtime.h>

#define T_TOK  2048
#define DIMD   1024
#define INTERI 512
#define NEXP   16
#define NSEG   17   // 16 routed + 1 shared (index 16)

typedef __bf16 bf16x8 __attribute__((ext_vector_type(8)));
typedef float  f32x4  __attribute__((ext_vector_type(4)));
typedef unsigned short u16x8 __attribute__((ext_vector_type(8)));

// XOR-swizzle (read side): chunk c (8 elems) of row r lives at slot (c + (r>>1)) & 3.
// Staging pre-swizzles the GLOBAL source per lane (m173 pattern):
// lane at slot s of row r fetches global chunk (s - (r>>1)) & 3, LDS dest linear.
#define SW(row, c) ((((c) + ((row) >> 1)) & 3) * 8)

// ---------- helpers ----------
__device__ __forceinline__ unsigned short f2b(float f) {
    union { float f; unsigned int u; } c; c.f = f;
    unsigned int u = c.u;
    unsigned int r = (u + 0x7FFFu + ((u >> 16) & 1u)) >> 16;  // RNE
    return (unsigned short)r;
}

// async global->LDS DMA, 16B per lane: dest = ldsbase + lane*16 (wave-uniform base)
__device__ __forceinline__ void glds16(const void* g, void* l) {
    __builtin_amdgcn_global_load_lds(
        (const __attribute__((address_space(1))) unsigned int*)g,
        (__attribute__((address_space(3))) unsigned int*)l,
        16, 0, 0);
}

// barrier that explicitly drains the DMA queue first (defensive)
__device__ __forceinline__ void dma_barrier() {
    asm volatile("s_waitcnt vmcnt(0)" ::: "memory");
    __syncthreads();
}

// ---------- prep: gate FIRST, then weight cvt, ONE launch ----------
// blocks [0,512): gate (one wave per token) + x->bf16   <- long blocks start at t=0
// blocks [512,3776): cvt, 32 floats/thread (8x float4 load, 4x 16B store)
__global__ __launch_bounds__(256) void prep_kernel(
    const float* __restrict__ w1,  const float* __restrict__ w3,
    const float* __restrict__ w2,
    const float* __restrict__ ws1, const float* __restrict__ ws3,
    const float* __restrict__ ws2,
    unsigned short* __restrict__ w1b,  unsigned short* __restrict__ w3b,
    unsigned short* __restrict__ w2b,
    unsigned short* __restrict__ ws1b, unsigned short* __restrict__ ws3b,
    unsigned short* __restrict__ ws2b,
    const float* __restrict__ x, const float* __restrict__ gw,
    const float* __restrict__ gb,
    unsigned* __restrict__ sel, float4* __restrict__ selw,
    unsigned short* __restrict__ xb)
{
    const int b = blockIdx.x;
    if (b >= 512) {
        // ---- weight conversion: 32 floats/thread ----
        int g = (b - 512) * 256 + threadIdx.x;    // chunk of 32 floats
        const float* s; unsigned short* d; int i;
        if      (g < 262144) { s = w1;  d = w1b;  i = g; }            // 8.39M/32
        else if (g < 524288) { s = w3;  d = w3b;  i = g - 262144; }
        else if (g < 786432) { s = w2;  d = w2b;  i = g - 524288; }
        else if (g < 802816) { s = ws1; d = ws1b; i = g - 786432; }   // 0.52M/32
        else if (g < 819200) { s = ws3; d = ws3b; i = g - 802816; }
        else                 { s = ws2; d = ws2b; i = g - 819200; }
        const f32x4* sp = (const f32x4*)s + 8 * (size_t)i;
        u16x8* dp = (u16x8*)d + 4 * (size_t)i;
#pragma unroll
        for (int q = 0; q < 4; ++q) {
            f32x4 v0 = sp[2 * q];
            f32x4 v1 = sp[2 * q + 1];
            u16x8 o;
            o[0] = f2b(v0[0]); o[1] = f2b(v0[1]); o[2] = f2b(v0[2]); o[3] = f2b(v0[3]);
            o[4] = f2b(v1[0]); o[5] = f2b(v1[1]); o[6] = f2b(v1[2]); o[7] = f2b(v1[3]);
            dp[q] = o;
        }
        return;
    }
    // ---- gate: scores + top-k selection + x->bf16 ----
    int tok  = b * 4 + (threadIdx.x >> 6);   // one wave per token
    int lane = threadIdx.x & 63;
    const float* xp = x + (size_t)tok * DIMD;
    float xv[16];
#pragma unroll
    for (int j = 0; j < 16; ++j) xv[j] = xp[j * 64 + lane];

    unsigned short* xbp = xb + (size_t)tok * DIMD;
#pragma unroll
    for (int j = 0; j < 16; ++j) xbp[j * 64 + lane] = f2b(xv[j]);

    float sc[16];
#pragma unroll
    for (int e = 0; e < 16; ++e) {
        const float* gwe = gw + e * DIMD;
        float p0 = 0.f, p1 = 0.f;
#pragma unroll
        for (int j = 0; j < 16; j += 2) {
            p0 += xv[j]     * gwe[j * 64 + lane];
            p1 += xv[j + 1] * gwe[(j + 1) * 64 + lane];
        }
        float p = p0 + p1;
#pragma unroll
        for (int o = 32; o; o >>= 1) p += __shfl_xor(p, o, 64);
        sc[e] = p;
    }
    if (lane != 0) return;

    float orig[16], s[16];
#pragma unroll
    for (int e = 0; e < 16; ++e) {
        orig[e] = 1.f / (1.f + expf(-sc[e]));
        s[e] = orig[e] + gb[e];
    }
    float gmax[4];
#pragma unroll
    for (int g = 0; g < 4; ++g) {
        float m = s[4 * g];
        for (int j = 1; j < 4; ++j) m = fmaxf(m, s[4 * g + j]);
        gmax[g] = m;
    }
    int g0 = 0;
    for (int g = 1; g < 4; ++g) if (gmax[g] > gmax[g0]) g0 = g;
    int g1 = -1;
    for (int g = 0; g < 4; ++g) { if (g == g0) continue; if (g1 < 0 || gmax[g] > gmax[g1]) g1 = g; }
    unsigned keep = (0xFu << (4 * g0)) | (0xFu << (4 * g1));
    unsigned used = 0;
    unsigned pk = 0;
    float w4[4];
    for (int j = 0; j < 4; ++j) {
        int best = -1;
        for (int e = 0; e < 16; ++e) {
            if (!((keep >> e) & 1u) || ((used >> e) & 1u)) continue;
            if (best < 0 || s[e] > s[best]) best = e;
        }
        used |= 1u << best;
        pk |= ((unsigned)best) << (4 * j);
        w4[j] = orig[best];
    }
    sel[tok] = pk;
    selw[tok] = make_float4(w4[0], w4[1], w4[2], w4[3]);
}

// ---------- gate phase 2: build per-expert token lists, NO atomics ----------
__global__ __launch_bounds__(256) void build_lists_kernel(
    const unsigned* __restrict__ sel, const float4* __restrict__ selw,
    int* __restrict__ counts, int* __restrict__ lst, float* __restrict__ lstw)
{
    const int e    = blockIdx.x;
    const int tid  = threadIdx.x;
    const int wave = tid >> 6;
    const int lane = tid & 63;

    __shared__ int wsum[4];
    __shared__ int basev;
    if (tid == 0) basev = 0;
    __syncthreads();

    for (int c = 0; c < T_TOK / 256; ++c) {
        int t = c * 256 + tid;
        unsigned s = sel[t];
        int match = -1;
#pragma unroll
        for (int j = 0; j < 4; ++j)
            if (((s >> (4 * j)) & 15u) == (unsigned)e) match = j;
        unsigned long long m = __ballot(match >= 0);
        int wpre = __popcll(m & ((1ull << lane) - 1ull));
        if (lane == 0) wsum[wave] = __popcll(m);
        __syncthreads();
        int pre = basev;
        for (int wv = 0; wv < wave; ++wv) pre += wsum[wv];
        if (match >= 0) {
            int pos = pre + wpre;
            lst [e * T_TOK + pos] = t | (match << 16);
            const float* wp = (const float*)&selw[t];
            lstw[e * T_TOK + pos] = wp[match];
        }
        __syncthreads();
        if (tid == 0) basev += wsum[0] + wsum[1] + wsum[2] + wsum[3];
        __syncthreads();
    }
    if (tid == 0) counts[e] = basev;
}

// ---------- GEMM1: H = silu(X W1^T) * (X W3^T) ----------
// 128x128 tile, wave tile 64x64 (dual h1/h3), BK=64.
// Staging via global_load_lds DMA (pre-swizzled global source, linear LDS dest).
// Per K-step: 12 DMA issues -> vmcnt(0)+sync -> ds_read+MFMA -> sync.
// grid: 1024 routed + 64 shared = 1088.
__global__ __launch_bounds__(256, 2) void gemm1_kernel(
    const unsigned short* __restrict__ xb,
    const unsigned short* __restrict__ w1b,
    const unsigned short* __restrict__ w3b,
    const unsigned short* __restrict__ ws1b,
    const unsigned short* __restrict__ ws3b,
    const int* __restrict__ counts,
    const int* __restrict__ lst,
    unsigned short* __restrict__ H)
{
    int b = blockIdx.x;
    int seg, mt, nt;
    if (b < 1024) {
        int xcd = b & 7, slot = b >> 3;     // slot 0..127
        seg = xcd + 8 * (slot >> 6);        // 2 experts per XCD
        int tile = slot & 63;
        mt = tile >> 2; nt = tile & 3;      // mt 0..15, nt 0..3
    } else {
        seg = NEXP;
        int tile = b - 1024;                // 0..63
        mt = tile >> 2; nt = tile & 3;
    }
    const int n_e = (seg == NEXP) ? T_TOK : counts[seg];
    const int m0  = mt * 128;
    if (m0 >= n_e) return;
    const int n0  = nt * 128;

    const unsigned short* w1p = (seg == NEXP) ? ws1b : w1b + (size_t)seg * INTERI * DIMD;
    const unsigned short* w3p = (seg == NEXP) ? ws3b : w3b + (size_t)seg * INTERI * DIMD;
    const int* lste = lst + seg * T_TOK;

    __shared__ __align__(16) unsigned short lA [2][128][32];   // 16 KB (kk-halves)
    __shared__ __align__(16) unsigned short lB1[2][128][32];   // 16 KB
    __shared__ __align__(16) unsigned short lB3[2][128][32];   // 16 KB

    const int tid  = threadIdx.x;
    const int wave = tid >> 6;
    const int lane = tid & 63;
    const int quad = lane >> 4;
    const int lrow = lane & 15;

    // DMA staging geometry: wave covers rows wave*32 + (lane>>2) (+16)
    const int lr  = lane >> 2;
    const int lsl = lane & 3;
    const int r0  = wave * 32 + lr, r1 = r0 + 16;
    const int c0  = (lsl - (r0 >> 1)) & 3;     // global chunk for slot lsl
    const int c1  = (lsl - (r1 >> 1)) & 3;
    int ga0 = m0 + r0; if (ga0 > n_e - 1) ga0 = n_e - 1;
    int ga1 = m0 + r1; if (ga1 > n_e - 1) ga1 = n_e - 1;
    const int tA0 = (seg == NEXP) ? ga0 : (lste[ga0] & 0xFFFF);
    const int tA1 = (seg == NEXP) ? ga1 : (lste[ga1] & 0xFFFF);
    const unsigned short* pA0  = xb  + (size_t)tA0 * DIMD + c0 * 8;
    const unsigned short* pA1  = xb  + (size_t)tA1 * DIMD + c1 * 8;
    const unsigned short* pB10 = w1p + (size_t)(n0 + r0) * DIMD + c0 * 8;
    const unsigned short* pB11 = w1p + (size_t)(n0 + r1) * DIMD + c1 * 8;
    const unsigned short* pB30 = w3p + (size_t)(n0 + r0) * DIMD + c0 * 8;
    const unsigned short* pB31 = w3p + (size_t)(n0 + r1) * DIMD + c1 * 8;

#define G1STAGE(k0) do { \
    glds16(pA0  + (k0),      &lA [0][wave * 32][0]); \
    glds16(pA0  + (k0) + 32, &lA [1][wave * 32][0]); \
    glds16(pA1  + (k0),      &lA [0][wave * 32 + 16][0]); \
    glds16(pA1  + (k0) + 32, &lA [1][wave * 32 + 16][0]); \
    glds16(pB10 + (k0),      &lB1[0][wave * 32][0]); \
    glds16(pB10 + (k0) + 32, &lB1[1][wave * 32][0]); \
    glds16(pB11 + (k0),      &lB1[0][wave * 32 + 16][0]); \
    glds16(pB11 + (k0) + 32, &lB1[1][wave * 32 + 16][0]); \
    glds16(pB30 + (k0),      &lB3[0][wave * 32][0]); \
    glds16(pB30 + (k0) + 32, &lB3[1][wave * 32][0]); \
    glds16(pB31 + (k0),      &lB3[0][wave * 32 + 16][0]); \
    glds16(pB31 + (k0) + 32, &lB3[1][wave * 32 + 16][0]); \
} while (0)

    f32x4 acc1[4][4], acc3[4][4];
    const f32x4 zero = {0.f, 0.f, 0.f, 0.f};
#pragma unroll
    for (int i = 0; i < 4; ++i)
#pragma unroll
        for (int j = 0; j < 4; ++j) { acc1[i][j] = zero; acc3[i][j] = zero; }

    const int wm = (wave & 1) * 64;
    const int wn = (wave >> 1) * 64;

    const int NK = DIMD / 64;  // 16
    for (int it = 0; it < NK; ++it) {
        G1STAGE(it * 64);
        dma_barrier();                     // DMA drained: tile in LDS
#pragma unroll
        for (int kk = 0; kk < 2; ++kk) {
            bf16x8 a[4], bv[4];
#pragma unroll
            for (int t = 0; t < 4; ++t) {
                int rr = wm + t * 16 + lrow;
                a[t] = *(const bf16x8*)&lA[kk][rr][SW(rr, quad)];
            }
#pragma unroll
            for (int t = 0; t < 4; ++t) {
                int rc = wn + t * 16 + lrow;
                bv[t] = *(const bf16x8*)&lB1[kk][rc][SW(rc, quad)];
            }
#pragma unroll
            for (int i = 0; i < 4; ++i)
#pragma unroll
                for (int j = 0; j < 4; ++j)
                    acc1[i][j] = __builtin_amdgcn_mfma_f32_16x16x32_bf16(a[i], bv[j], acc1[i][j], 0, 0, 0);
#pragma unroll
            for (int t = 0; t < 4; ++t) {
                int rc = wn + t * 16 + lrow;
                bv[t] = *(const bf16x8*)&lB3[kk][rc][SW(rc, quad)];
            }
#pragma unroll
            for (int i = 0; i < 4; ++i)
#pragma unroll
                for (int j = 0; j < 4; ++j)
                    acc3[i][j] = __builtin_amdgcn_mfma_f32_16x16x32_bf16(a[i], bv[j], acc3[i][j], 0, 0, 0);
        }
        __syncthreads();                   // LDS reads done before next DMA overwrite
    }
#undef G1STAGE

    unsigned short* Hseg = H + (size_t)seg * T_TOK * INTERI;
#pragma unroll
    for (int i = 0; i < 4; ++i) {
        int rbase = m0 + wm + i * 16 + quad * 4;
#pragma unroll
        for (int r = 0; r < 4; ++r) {
            int row = rbase + r;
            if (row >= n_e) continue;
            unsigned short* hrow = Hseg + (size_t)row * INTERI + n0 + wn + lrow;
#pragma unroll
            for (int j = 0; j < 4; ++j) {
                float v1 = acc1[i][j][r];
                float v3 = acc3[i][j][r];
                float hv = (v1 / (1.f + __expf(-v1))) * v3;   // silu(v1)*v3
                hrow[j * 16] = f2b(hv);
            }
        }
    }
}

// ---------- GEMM2: P[slot] = w * (H W2^T), 128x128 tile, atomic-free ----------
// All-bf16; staging via global_load_lds DMA (8 issues/K-step).
// grid: 2048 routed slots + 128 shared = 2176.
__global__ __launch_bounds__(256, 2) void gemm2_kernel(
    const unsigned short* __restrict__ H,
    const unsigned short* __restrict__ w2b,
    const unsigned short* __restrict__ ws2b,
    const int* __restrict__ counts,
    const int* __restrict__ lst,
    const float* __restrict__ lstw,
    float* __restrict__ P)
{
    int b = blockIdx.x;
    int seg, mt, nt;
    if (b < 2048) {
        int xcd = b & 7, slot = b >> 3;     // 0..255
        seg = xcd + 8 * (slot >> 7);
        int tile = slot & 127;
        mt = tile >> 3; nt = tile & 7;      // mt 0..15, nt 0..7
    } else {
        seg = NEXP;
        int tile = b - 2048;                // 0..127
        mt = tile >> 3; nt = tile & 7;
    }
    const int n_e = (seg == NEXP) ? T_TOK : counts[seg];
    const int m0  = mt * 128;
    if (m0 >= n_e) return;
    const int n0  = nt * 128;

    const unsigned short* w2p  = (seg == NEXP) ? ws2b : w2b + (size_t)seg * DIMD * INTERI;
    const unsigned short* Hseg = H + (size_t)seg * T_TOK * INTERI;

    __shared__ __align__(16) unsigned short lA[2][128][32];   // 16 KB
    __shared__ __align__(16) unsigned short lB[2][128][32];   // 16 KB

    const int tid  = threadIdx.x;
    const int wave = tid >> 6;
    const int lane = tid & 63;
    const int quad = lane >> 4;
    const int lrow = lane & 15;

    const int lr  = lane >> 2;
    const int lsl = lane & 3;
    const int r0  = wave * 32 + lr, r1 = r0 + 16;
    const int c0  = (lsl - (r0 >> 1)) & 3;
    const int c1  = (lsl - (r1 >> 1)) & 3;
    int ga0 = m0 + r0; if (ga0 > n_e - 1) ga0 = n_e - 1;
    int ga1 = m0 + r1; if (ga1 > n_e - 1) ga1 = n_e - 1;
    const unsigned short* pA0 = Hseg + (size_t)ga0 * INTERI + c0 * 8;
    const unsigned short* pA1 = Hseg + (size_t)ga1 * INTERI + c1 * 8;
    const unsigned short* pB0 = w2p + (size_t)(n0 + r0) * INTERI + c0 * 8;
    const unsigned short* pB1 = w2p + (size_t)(n0 + r1) * INTERI + c1 * 8;

#define G2STAGE(k0) do { \
    glds16(pA0 + (k0),      &lA[0][wave * 32][0]); \
    glds16(pA0 + (k0) + 32, &lA[1][wave * 32][0]); \
    glds16(pA1 + (k0),      &lA[0][wave * 32 + 16][0]); \
    glds16(pA1 + (k0) + 32, &lA[1][wave * 32 + 16][0]); \
    glds16(pB0 + (k0),      &lB[0][wave * 32][0]); \
    glds16(pB0 + (k0) + 32, &lB[1][wave * 32][0]); \
    glds16(pB1 + (k0),      &lB[0][wave * 32 + 16][0]); \
    glds16(pB1 + (k0) + 32, &lB[1][wave * 32 + 16][0]); \
} while (0)

    f32x4 acc[4][4];
    const f32x4 zero = {0.f, 0.f, 0.f, 0.f};
#pragma unroll
    for (int i = 0; i < 4; ++i)
#pragma unroll
        for (int j = 0; j < 4; ++j) acc[i][j] = zero;

    const int wm = (wave & 1) * 64;
    const int wn = (wave >> 1) * 64;

    const int NK = INTERI / 64;  // 8
    for (int it = 0; it < NK; ++it) {
        G2STAGE(it * 64);
        dma_barrier();
#pragma unroll
        for (int kk = 0; kk < 2; ++kk) {
            bf16x8 a[4], bv[4];
#pragma unroll
            for (int t = 0; t < 4; ++t) {
                int rr = wm + t * 16 + lrow;
                a[t] = *(const bf16x8*)&lA[kk][rr][SW(rr, quad)];
            }
#pragma unroll
            for (int t = 0; t < 4; ++t) {
                int rc = wn + t * 16 + lrow;
                bv[t] = *(const bf16x8*)&lB[kk][rc][SW(rc, quad)];
            }
#pragma unroll
            for (int i = 0; i < 4; ++i)
#pragma unroll
                for (int j = 0; j < 4; ++j)
                    acc[i][j] = __builtin_amdgcn_mfma_f32_16x16x32_bf16(a[i], bv[j], acc[i][j], 0, 0, 0);
        }
        __syncthreads();
    }
#undef G2STAGE

#pragma unroll
    for (int i = 0; i < 4; ++i) {
        int rbase = m0 + wm + i * 16 + quad * 4;
#pragma unroll
        for (int r = 0; r < 4; ++r) {
            int row = rbase + r;
            if (row >= n_e) continue;
            int tok, slot; float wt;
            if (seg == NEXP) { tok = row; slot = 4; wt = 1.f; }
            else {
                int ent = lst[seg * T_TOK + row];
                tok = ent & 0xFFFF; slot = ent >> 16;
                wt = lstw[seg * T_TOK + row];
            }
            float* prow = P + ((size_t)slot * T_TOK + tok) * DIMD + n0 + wn + lrow;
#pragma unroll
            for (int j = 0; j < 4; ++j)
                prow[j * 16] = wt * acc[i][j][r];
        }
    }
}

// ---------- combine: y = P0+P1+P2+P3+P4 ----------
__global__ __launch_bounds__(256) void combine_kernel(
    const float4* __restrict__ P, float4* __restrict__ y)
{
    const int i = blockIdx.x * 256 + threadIdx.x;   // over T*D/4
    const size_t plane = (size_t)T_TOK * DIMD / 4;
    float4 a = P[i];
    float4 b = P[plane + i];
    float4 c = P[2 * plane + i];
    float4 d = P[3 * plane + i];
    float4 e = P[4 * plane + i];
    float4 o;
    o.x = a.x + b.x + c.x + d.x + e.x;
    o.y = a.y + b.y + c.y + d.y + e.y;
    o.z = a.z + b.z + c.z + d.z + e.z;
    o.w = a.w + b.w + c.w + d.w + e.w;
    y[i] = o;
}

// ---------- launcher ----------
extern "C" void kernel_launch(void* const* d_in, const int* in_sizes, int n_in,
                              void* d_out, int out_size, void* d_ws, size_t ws_size,
                              hipStream_t stream)
{
    const float* x   = (const float*)d_in[0];
    const float* gw  = (const float*)d_in[1];
    const float* gb  = (const float*)d_in[2];
    const float* w1  = (const float*)d_in[3];
    const float* w2  = (const float*)d_in[4];
    const float* w3  = (const float*)d_in[5];
    const float* ws1 = (const float*)d_in[6];
    const float* ws2 = (const float*)d_in[7];
    const float* ws3 = (const float*)d_in[8];

    char* base = (char*)d_ws;
    size_t off = 0;
    auto alloc = [&](size_t bytes) {
        char* q = base + off; off += (bytes + 255) & ~(size_t)255; return q;
    };
    unsigned short* xb   = (unsigned short*)alloc((size_t)T_TOK * DIMD * 2);
    unsigned short* w1b  = (unsigned short*)alloc((size_t)NEXP * INTERI * DIMD * 2);
    unsigned short* w3b  = (unsigned short*)alloc((size_t)NEXP * INTERI * DIMD * 2);
    unsigned short* w2b  = (unsigned short*)alloc((size_t)NEXP * DIMD * INTERI * 2);
    unsigned short* ws1b = (unsigned short*)alloc((size_t)INTERI * DIMD * 2);
    unsigned short* ws3b = (unsigned short*)alloc((size_t)INTERI * DIMD * 2);
    unsigned short* ws2b = (unsigned short*)alloc((size_t)DIMD * INTERI * 2);
    unsigned short* Hb   = (unsigned short*)alloc((size_t)NSEG * T_TOK * INTERI * 2);
    int*            cnts = (int*)alloc(NEXP * 4);
    int*            lstp = (int*)alloc((size_t)NEXP * T_TOK * 4);
    float*          lstw = (float*)alloc((size_t)NEXP * T_TOK * 4);
    unsigned*       selp = (unsigned*)alloc((size_t)T_TOK * 4);
    float4*         selw = (float4*)alloc((size_t)T_TOK * 16);
    float*          Pb   = (float*)alloc((size_t)5 * T_TOK * DIMD * 4);

    // prep grid: 512 gate blocks FIRST, then 3264 cvt blocks (32 floats/thread)
    prep_kernel<<<3776, 256, 0, stream>>>(w1, w3, w2, ws1, ws3, ws2,
                                          w1b, w3b, w2b, ws1b, ws3b, ws2b,
                                          x, gw, gb, selp, selw, xb);
    build_lists_kernel<<<NEXP, 256, 0, stream>>>(selp, selw, cnts, lstp, lstw);
    gemm1_kernel<<<1088, 256, 0, stream>>>(xb, w1b, w3b, ws1b, ws3b, cnts, lstp, Hb);
    gemm2_kernel<<<2176, 256, 0, stream>>>(Hb, w2b, ws2b, cnts, lstp, lstw, Pb);
    combine_kernel<<<(T_TOK * DIMD / 4) / 256, 256, 0, stream>>>((const float4*)Pb, (float4*)d_out);
}